// Round 12
// baseline (37.554 us; speedup 1.0000x reference)
//
#include <hip/hip_runtime.h>

#define NFEAT 40
#define EMB   64
#define ATT   32
#define NPAIR 780
#define NTILE 49      // 49 tiles x 16 pairs = 784 (padded)
#define XH_S  72      // fp16 x LDS stride (elems) -> 144 B row stride
#define XREG  (NFEAT * XH_S)   // 2880 elems = 5760 B per batch region

typedef __attribute__((ext_vector_type(8))) _Float16 f16x8;
typedef __attribute__((ext_vector_type(4))) _Float16 f16x4;
typedef __attribute__((ext_vector_type(4))) float    f32x4;
typedef __attribute__((ext_vector_type(2))) unsigned u32x2;

template <int CTRL>
__device__ __forceinline__ float dpp_add_f(float v) {
  int t = __builtin_amdgcn_update_dpp(0, __float_as_int(v), CTRL, 0xF, 0xF, true);
  return v + __int_as_float(t);
}
__device__ __forceinline__ float rowsum16(float v) {
  v = dpp_add_f<0x128>(v);
  v = dpp_add_f<0x124>(v);
  v = dpp_add_f<0x122>(v);
  v = dpp_add_f<0x121>(v);
  return v;
}

// sum over the 4 16-lane rows (atts' hk groups) — VALU permlanes, not DS
__device__ __forceinline__ float xgroup_sum(float v) {
#if __has_builtin(__builtin_amdgcn_permlane16_swap) && __has_builtin(__builtin_amdgcn_permlane32_swap)
  {
    auto a = __builtin_amdgcn_permlane16_swap(__float_as_uint(v), __float_as_uint(v), false, false);
    v = __uint_as_float(a[0]) + __uint_as_float(a[1]);
    auto b = __builtin_amdgcn_permlane32_swap(__float_as_uint(v), __float_as_uint(v), false, false);
    v = __uint_as_float(b[0]) + __uint_as_float(b[1]);
  }
#else
  v += __shfl_xor(v, 16, 64);
  v += __shfl_xor(v, 32, 64);
#endif
  return v;
}

__device__ __forceinline__ int pair_off(int i) { return 39 * i - (i * (i - 1)) / 2; }

extern "C" __global__ __launch_bounds__(256)
void afm_kernel(const float* __restrict__ xg, const float* __restrict__ Wg,
                const float* __restrict__ bg, const float* __restrict__ hg,
                const float* __restrict__ pg, float* __restrict__ outg, int nbatch) {
  __shared__ __align__(16) _Float16 xh[2 * XREG];   // 11520 B (2 batch regions)
  __shared__ unsigned prtp[25 * 32];                // 3200 B, [tilepair][l15][2]
  __shared__ float red[4][2];

  const int tid  = threadIdx.x;
  const int lane = tid & 63, wid = tid >> 6;
  const int l15  = lane & 15, hk = lane >> 4;
  const int half = wid & 1;                          // tile-range half
  const int breg = wid >> 1;                         // batch region 0/1
  const int bb   = blockIdx.x * 2 + breg;            // one batch per wave PAIR
  const bool live = bb < nbatch;

  // ---- pair table -> LDS, pair-packed for ds_read_b64 ----
  for (int p = tid; p < NTILE * 16; p += 256) {
    int i = 0, j = 0;
    if (p < NPAIR) {
      i = (int)((79.0f - sqrtf(6241.0f - 8.0f * (float)p)) * 0.5f);
      if (i < 0) i = 0;
      while (pair_off(i + 1) <= p) ++i;
      while (pair_off(i) > p) --i;
      j = i + 1 + (p - pair_off(i));
    }
    int t = p >> 4, l = p & 15;
    prtp[(t >> 1) * 32 + l * 2 + (t & 1)] =
        (unsigned)(i * 144) | ((unsigned)(j * 144) << 16);
  }

  // ---- W fragments (A operand; D = [att][pair]); wf2 row0 = p ----
  f16x8 wf0[2], wf1[2], wf2[2];
#pragma unroll
  for (int kk = 0; kk < 2; kk++) {
    f16x8 r0, r1, r2;
#pragma unroll
    for (int t = 0; t < 8; t++) {
      int krow = kk * 32 + hk * 8 + t;
      r0[t] = (_Float16)Wg[krow * ATT + l15];
      r1[t] = (_Float16)Wg[krow * ATT + 16 + l15];
      _Float16 pv = (_Float16)pg[krow];
      r2[t] = (l15 == 0) ? pv : (_Float16)0.f;
    }
    wf0[kk] = r0; wf1[kk] = r1; wf2[kk] = r2;
  }
  const float4 b0 = *(const float4*)&bg[hk * 4];
  const float4 b1 = *(const float4*)&bg[16 + hk * 4];
  const f32x4 cb0 = {b0.x, b0.y, b0.z, b0.w};
  const f32x4 cb1 = {b1.x, b1.y, b1.z, b1.w};
  // fold log2(e) into h -> logit in log2 domain, exp2f is bare v_exp_f32
  const float L2E = 1.4426950408889634f;
  float4 h0 = *(const float4*)&hg[hk * 4];
  float4 h1 = *(const float4*)&hg[16 + hk * 4];
  h0.x *= L2E; h0.y *= L2E; h0.z *= L2E; h0.w *= L2E;
  h1.x *= L2E; h1.y *= L2E; h1.z *= L2E; h1.w *= L2E;
  const f32x4 kz = {0.f, 0.f, 0.f, 0.f};

  // ---- stage own batch region; wave pair splits the 640 float4s ----
  if (live) {
    const float4* xsrc = (const float4*)(xg + (size_t)bb * (NFEAT * EMB));
    _Float16* xw = &xh[breg * XREG];
#pragma unroll
    for (int f = lane + half * 64; f < NFEAT * EMB / 4; f += 128) {
      float4 v = xsrc[f];
      int row = f >> 4, c = (f & 15) * 4;
      f16x4 h4 = {(_Float16)v.x, (_Float16)v.y, (_Float16)v.z, (_Float16)v.w};
      *(f16x4*)&xw[row * XH_S + c] = h4;
    }
  }
  __syncthreads();   // prt + staging visible; waves free-run after this

  float sum_e = 0.f, sum_es = 0.f;
  const unsigned wh = (unsigned)(breg * (XREG * 2) + hk * 16);  // byte base

  auto tile = [&](unsigned pij, bool full) {
    const unsigned offi = (pij & 0xFFFFu) + wh;
    const unsigned offj = (pij >> 16) + wh;
    const f16x8 xi0 = *(const f16x8*)((const char*)xh + offi);
    const f16x8 xj0 = *(const f16x8*)((const char*)xh + offj);
    const f16x8 xi1 = *(const f16x8*)((const char*)xh + offi + 64);
    const f16x8 xj1 = *(const f16x8*)((const char*)xh + offj + 64);
    f16x8 af0 = xi0 * xj0;
    f16x8 af1 = xi1 * xj1;
    f32x4 acc0 = __builtin_amdgcn_mfma_f32_16x16x32_f16(wf0[0], af0, cb0, 0, 0, 0);
    f32x4 acc1 = __builtin_amdgcn_mfma_f32_16x16x32_f16(wf1[0], af0, cb1, 0, 0, 0);
    f32x4 acc2 = __builtin_amdgcn_mfma_f32_16x16x32_f16(wf2[0], af0, kz, 0, 0, 0);
    acc0 = __builtin_amdgcn_mfma_f32_16x16x32_f16(wf0[1], af1, acc0, 0, 0, 0);
    acc1 = __builtin_amdgcn_mfma_f32_16x16x32_f16(wf1[1], af1, acc1, 0, 0, 0);
    acc2 = __builtin_amdgcn_mfma_f32_16x16x32_f16(wf2[1], af1, acc2, 0, 0, 0);
    float va = fmaf(fmaxf(acc0[0], 0.f), h0.x,
               fmaf(fmaxf(acc0[1], 0.f), h0.y,
               fmaf(fmaxf(acc0[2], 0.f), h0.z,
                    fmaxf(acc0[3], 0.f) * h0.w)));
    float vb = fmaf(fmaxf(acc1[0], 0.f), h1.x,
               fmaf(fmaxf(acc1[1], 0.f), h1.y,
               fmaf(fmaxf(acc1[2], 0.f), h1.z,
                    fmaxf(acc1[3], 0.f) * h1.w)));
    float v = xgroup_sum(va + vb);        // VALU permlanes
    float e = exp2f(v);                   // h pre-scaled by log2e
    if (!full) e = (l15 < 12) ? e : 0.f;  // pairs 780..783 pad
    sum_e += e;                           // identical across hk rows
    sum_es = fmaf(e, acc2[0], sum_es);    // acc2[0]==0 unless hk==0
  };

  if (live) {
    // half 0: tile-pairs 0..11 (tiles 0-23) + peeled tile 48
    // half 1: tile-pairs 12..23 (tiles 24-47)
    const int k0 = half ? 12 : 0;
    const int k1 = half ? 24 : 12;
#pragma unroll 4
    for (int k = k0; k < k1; ++k) {
      u32x2 pp = *(const u32x2*)&prtp[k * 32 + l15 * 2];
      tile(pp[0], true);
      tile(pp[1], true);
    }
    if (!half) tile(prtp[24 * 32 + l15 * 2], false);

    sum_e  = rowsum16(sum_e);
    sum_es = rowsum16(sum_es);
    if (lane == 0) { red[wid][0] = sum_e; red[wid][1] = sum_es; }
  }
  __syncthreads();
  if (live && lane == 0 && half == 0) {
    float Z = red[wid][0] + red[wid + 1][0];
    float S = red[wid][1] + red[wid + 1][1];
    outg[bb] = S / Z;
  }
}

extern "C" void kernel_launch(void* const* d_in, const int* in_sizes, int n_in,
                              void* d_out, int out_size, void* d_ws, size_t ws_size,
                              hipStream_t stream) {
  const float* xg = (const float*)d_in[0];
  const float* Wg = (const float*)d_in[1];
  const float* bg = (const float*)d_in[2];
  const float* hg = (const float*)d_in[3];
  const float* pg = (const float*)d_in[4];
  float* outg = (float*)d_out;
  const int Bn = in_sizes[0] / (NFEAT * EMB);
  const int nblk = (Bn + 1) / 2;
  afm_kernel<<<dim3(nblk), dim3(256), 0, stream>>>(xg, Wg, bg, hg, pg, outg, Bn);
}